// Round 1
// baseline (882.481 us; speedup 1.0000x reference)
//
#include <hip/hip_runtime.h>

// Problem constants (fixed by the reference)
#define B_ 8
#define L_ 1024
#define S_ 1024
#define H_ 12
#define E_ 64
#define D_ 64

#define TL 32      // query rows per block
#define TS 64      // key/value rows staged per iteration
#define NT 512     // threads per block (8 waves)
#define NITER (S_ / TS)  // 16

// LDS padded row widths (in bf16 elements). Rows stay 16B-aligned and the
// +8 pad gives a 2-way (free) bank pattern for the b128 fragment reads.
#define QW (E_ + 8)   // 72  -> 144B rows
#define KW (E_ + 8)   // 72
#define VW (TS + 8)   // 72
#define PW (S_ + 8)   // 1032 -> 2064B rows (2064%16==0, stride 516dw -> 2-way)

typedef short bf8 __attribute__((ext_vector_type(8)));   // 8 x bf16 (4 VGPRs)
typedef float f32x4 __attribute__((ext_vector_type(4))); // MFMA accumulator

__device__ __forceinline__ unsigned short f2bf(float f) {
  unsigned int u = __builtin_bit_cast(unsigned int, f);
  u += 0x7fffu + ((u >> 16) & 1u);   // round-to-nearest-even
  return (unsigned short)(u >> 16);
}
__device__ __forceinline__ float bf2f(unsigned short us) {
  unsigned int u = ((unsigned int)us) << 16;
  return __builtin_bit_cast(float, u);
}

__global__ __launch_bounds__(NT, 1) void attn_fused(
    const float* __restrict__ Q, const float* __restrict__ K,
    const float* __restrict__ V, const float* __restrict__ SC,
    float* __restrict__ OUTV, float* __restrict__ OUTA)
{
  __shared__ __align__(16) unsigned short Qs[TL * QW];
  __shared__ __align__(16) unsigned short Ks[TS * KW];
  __shared__ __align__(16) unsigned short Vt[D_ * VW];   // transposed: [d][s]
  __shared__ __align__(16) unsigned short P[TL * PW];    // unnormalized probs
  __shared__ float rowsum[TL];
  __shared__ float rinv[TL];

  const int t = threadIdx.x;

  // XCD-grouped mapping: blocks sharing (b,h) land on the same XCD (i%8
  // round-robin heuristic) so K/V re-reads hit that XCD's L2.
  const int blk = blockIdx.x;
  const int x   = blk & 7;     // xcd
  const int j   = blk >> 3;    // 0..383
  const int bh  = x * 12 + (j >> 5);   // 0..95
  const int lt  = j & 31;
  const int b   = bh / H_;
  const int h   = bh - b * H_;
  const int l0  = lt * TL;

  const float scale_h = SC[h];

  const int w    = t >> 6;       // wave 0..7
  const int lane = t & 63;
  const int quad = lane >> 4;    // 0..3
  const int l16  = lane & 15;
  const int rowblk  = w & 1;     // which 16-row block
  const int colblk  = w >> 1;    // which 16-col block (of 64) / d-block in PV
  const int rowbase = rowblk * 16;

  if (t < TL) rowsum[t] = 0.0f;

  // ---- stage Q tile: 32 x 64 fp32 -> bf16 LDS ----
  {
    const int r = t >> 4;            // 0..31
    const int c = (t & 15) * 4;      // 0..60
    const float4 q4 = *reinterpret_cast<const float4*>(
        Q + (((size_t)(b * L_ + l0 + r) * H_ + h) * E_ + c));
    unsigned short* dst = &Qs[r * QW + c];
    dst[0] = f2bf(q4.x); dst[1] = f2bf(q4.y);
    dst[2] = f2bf(q4.z); dst[3] = f2bf(q4.w);
  }

  // ---- QK^T + exp, P into LDS ----
  float psum[4] = {0.f, 0.f, 0.f, 0.f};
  const int krow = t >> 3;          // 0..63
  const int kcol = (t & 7) * 8;     // 0..56

  for (int it = 0; it < NITER; ++it) {
    __syncthreads();  // protect Ks (prev iter reads) + Qs initial staging
    {
      const int s = it * TS + krow;
      const float* src = K + (((size_t)(b * S_ + s) * H_ + h) * E_ + kcol);
      const float4 a0 = *reinterpret_cast<const float4*>(src);
      const float4 a1 = *reinterpret_cast<const float4*>(src + 4);
      unsigned short* dst = &Ks[krow * KW + kcol];
      dst[0] = f2bf(a0.x); dst[1] = f2bf(a0.y);
      dst[2] = f2bf(a0.z); dst[3] = f2bf(a0.w);
      dst[4] = f2bf(a1.x); dst[5] = f2bf(a1.y);
      dst[6] = f2bf(a1.z); dst[7] = f2bf(a1.w);
    }
    __syncthreads();

    f32x4 sacc = {0.f, 0.f, 0.f, 0.f};
    {
      const bf8 a0 = *(const bf8*)&Qs[(rowbase + l16) * QW + 0  + quad * 8];
      const bf8 b0 = *(const bf8*)&Ks[(colblk * 16 + l16) * KW + 0  + quad * 8];
      sacc = __builtin_amdgcn_mfma_f32_16x16x32_bf16(a0, b0, sacc, 0, 0, 0);
      const bf8 a1 = *(const bf8*)&Qs[(rowbase + l16) * QW + 32 + quad * 8];
      const bf8 b1 = *(const bf8*)&Ks[(colblk * 16 + l16) * KW + 32 + quad * 8];
      sacc = __builtin_amdgcn_mfma_f32_16x16x32_bf16(a1, b1, sacc, 0, 0, 0);
    }

    const int sg = it * TS + colblk * 16 + l16;  // global key col of this lane
#pragma unroll
    for (int r = 0; r < 4; ++r) {
      const int lrow = rowbase + quad * 4 + r;   // local query row
      const int lg = l0 + lrow;                  // global query row
      float p = __expf(sacc[r] * scale_h);
      if (sg == lg) p = 0.f;                     // diagonal LSA mask -> A=0
      P[lrow * PW + it * TS + colblk * 16 + l16] = f2bf(p);
      psum[r] += p;
    }
  }

  // ---- row sums: reduce across the 16 cols held by the quad's lanes ----
#pragma unroll
  for (int r = 0; r < 4; ++r) {
    float v = psum[r];
    v += __shfl_xor(v, 8, 16);
    v += __shfl_xor(v, 4, 16);
    v += __shfl_xor(v, 2, 16);
    v += __shfl_xor(v, 1, 16);
    if (l16 == 0) atomicAdd(&rowsum[rowbase + quad * 4 + r], v);
  }
  __syncthreads();
  if (t < TL) rinv[t] = 1.0f / rowsum[t];
  __syncthreads();

  // ---- write A = P * rinv (fp32, coalesced float4) ----
  {
    const size_t abase = (((size_t)(b * H_ + h)) * L_ + l0) * S_;
#pragma unroll
    for (int itw = 0; itw < 16; ++itw) {
      const int flat4 = itw * NT + t;     // 0..8191
      const int row = flat4 >> 8;         // 256 float4 per row
      const int c4  = flat4 & 255;
      const unsigned short* ps = &P[row * PW + c4 * 4];
      const float ri = rinv[row];
      float4 o;
      o.x = bf2f(ps[0]) * ri;
      o.y = bf2f(ps[1]) * ri;
      o.z = bf2f(ps[2]) * ri;
      o.w = bf2f(ps[3]) * ri;
      *reinterpret_cast<float4*>(OUTA + abase + (size_t)row * S_ + c4 * 4) = o;
    }
  }

  // ---- PV: O = P @ V (V staged transposed so B-frag is contiguous) ----
  f32x4 oacc = {0.f, 0.f, 0.f, 0.f};
  const int vrow = t >> 3;         // s_local 0..63
  const int vcol = (t & 7) * 8;    // d0

  for (int it = 0; it < NITER; ++it) {
    __syncthreads();  // protect Vt from previous iteration's reads
    {
      const int s = it * TS + vrow;
      const float* src = V + (((size_t)(b * S_ + s) * H_ + h) * D_ + vcol);
      const float4 a0 = *reinterpret_cast<const float4*>(src);
      const float4 a1 = *reinterpret_cast<const float4*>(src + 4);
      Vt[(vcol + 0) * VW + vrow] = f2bf(a0.x);
      Vt[(vcol + 1) * VW + vrow] = f2bf(a0.y);
      Vt[(vcol + 2) * VW + vrow] = f2bf(a0.z);
      Vt[(vcol + 3) * VW + vrow] = f2bf(a0.w);
      Vt[(vcol + 4) * VW + vrow] = f2bf(a1.x);
      Vt[(vcol + 5) * VW + vrow] = f2bf(a1.y);
      Vt[(vcol + 6) * VW + vrow] = f2bf(a1.z);
      Vt[(vcol + 7) * VW + vrow] = f2bf(a1.w);
    }
    __syncthreads();

    const bf8 pa0 = *(const bf8*)&P[(rowbase + l16) * PW + it * TS + 0  + quad * 8];
    const bf8 vb0 = *(const bf8*)&Vt[(colblk * 16 + l16) * VW + 0  + quad * 8];
    oacc = __builtin_amdgcn_mfma_f32_16x16x32_bf16(pa0, vb0, oacc, 0, 0, 0);
    const bf8 pa1 = *(const bf8*)&P[(rowbase + l16) * PW + it * TS + 32 + quad * 8];
    const bf8 vb1 = *(const bf8*)&Vt[(colblk * 16 + l16) * VW + 32 + quad * 8];
    oacc = __builtin_amdgcn_mfma_f32_16x16x32_bf16(pa1, vb1, oacc, 0, 0, 0);
  }

  // ---- write V output (normalize by rinv here: P was unnormalized) ----
#pragma unroll
  for (int r = 0; r < 4; ++r) {
    const int lrow = rowbase + quad * 4 + r;
    const int lg = l0 + lrow;
    const float ri = rinv[lrow];
    OUTV[(((size_t)(b * L_ + lg)) * H_ + h) * D_ + colblk * 16 + l16] =
        oacc[r] * ri;
  }
}

extern "C" void kernel_launch(void* const* d_in, const int* in_sizes, int n_in,
                              void* d_out, int out_size, void* d_ws, size_t ws_size,
                              hipStream_t stream) {
  (void)in_sizes; (void)n_in; (void)out_size; (void)d_ws; (void)ws_size;
  const float* Q  = (const float*)d_in[0];
  const float* K  = (const float*)d_in[1];
  const float* V  = (const float*)d_in[2];
  const float* SC = (const float*)d_in[3];
  float* OUTV = (float*)d_out;
  float* OUTA = OUTV + (size_t)B_ * L_ * H_ * D_;   // tuple order: (V, A)

  const dim3 grid(B_ * H_ * (L_ / TL));  // 3072 blocks
  attn_fused<<<grid, NT, 0, stream>>>(Q, K, V, SC, OUTV, OUTA);
}